// Round 10
// baseline (75.430 us; speedup 1.0000x reference)
//
#include <hip/hip_runtime.h>
#include <stdint.h>

#define BTOT 8192
#define NSS  4096
#define LL   64
#define BT   512           // batches per block (8 waves x 64)
#define WB   64            // batches per wave
#define STT  32            // states per tile
#define NT   (NSS/STT)     // 128 state tiles total
#define NSPLIT 16          // state splits across blocks
#define TPS  (NT/NSPLIT)   // 8 tiles per split; all staged in LDS at once
#define TILEB 8192         // packed bytes per tile: 4 f16 frags + 4 bf16 frags
#define JROWB 72           // padded LDS row bytes for J tile (64B data + 8 pad)
#define JBUFB (64 * JROWB) // one J buffer: 64 batch rows

typedef __bf16    bf16x8 __attribute__((ext_vector_type(8)));
typedef _Float16  f16x8  __attribute__((ext_vector_type(8)));
typedef float     f32x4  __attribute__((ext_vector_type(4)));

static __device__ __forceinline__ unsigned short f2bf(float x){
  union { float f; uint32_t u; } v; v.f = x;
  uint32_t r = v.u + 0x7fffu + ((v.u >> 16) & 1u);
  return (unsigned short)(r >> 16);
}

// Pack S into per-tile 8KB blobs, fragment-ordered (same as round 9):
//   blob[t][frag*1024 + lane*16], frag 0..3: f16 GEMM1 A-frags (ss*2+kc)
//   blob[t][4096 + lt*1024 + lane*16], lt 0..3: bf16 GEMM2 A-frags
// Also zeroes out[0] (loss accumulator for finalize's atomicAdd).
__global__ void prepack_kernel(const float* __restrict__ S,
                               unsigned char* __restrict__ Spack,
                               float* __restrict__ out){
  const int t = blockIdx.x;
  const int sbase = t * STT;
  if (t == 0 && threadIdx.x == 0) out[0] = 0.f;
  #pragma unroll
  for (int rep = 0; rep < 2; ++rep){
    int item = rep * 256 + threadIdx.x;    // 0..511
    int frag = item >> 6;                  // 0..7
    int lane = item & 63;
    int c16 = lane & 15, q4 = lane >> 4;
    if (frag < 4){
      int ss = frag >> 1, kc = frag & 1;
      const float* row = S + (size_t)(sbase + ss*16 + c16)*LL + kc*32 + q4*8;
      f16x8 h;
      #pragma unroll
      for (int j = 0; j < 8; ++j) h[j] = (_Float16)row[j];   // 0/1 exact
      *(f16x8*)&Spack[(size_t)t*TILEB + frag*1024 + lane*16] = h;
    } else {
      int lt = frag - 4;
      int l  = lt*16 + c16;
      int s0 = sbase + q4*8;
      union { unsigned short u[8]; bf16x8 v; } H;
      #pragma unroll
      for (int j = 0; j < 8; ++j) H.u[j] = f2bf(S[(size_t)(s0 + j)*LL + l]);  // 0/1 exact
      *(bf16x8*)&Spack[(size_t)t*TILEB + 4096 + lt*1024 + lane*16] = H.v;
    }
  }
}

// 8 waves x 64 batches; the block's WHOLE tile slab (8 tiles, 64KB) is staged in
// LDS once (single barrier), then waves free-run independently over all tiles:
// GEMM2 deferred one tile (J RAW covered), a2 re-read from the persistent stage.
__launch_bounds__(512, 2)
__global__ void fused_kernel(const float* __restrict__ f,
                             const unsigned char* __restrict__ Spack,
                             float* __restrict__ numPart,   // [NSPLIT][BTOT][LL]
                             float* __restrict__ zPart){    // [NSPLIT][BTOT]
  const int tid  = threadIdx.x;
  const int w    = tid >> 6;                 // wave 0..7
  const int lane = tid & 63;
  const int c16  = lane & 15;
  const int q4   = lane >> 4;
  const int bt   = blockIdx.x & 15;          // 16 batch-blocks
  const int sp   = blockIdx.x >> 4;          // state split 0..15
  const int bb   = bt * BT + w * WB;         // this wave's batch base

  __shared__ __align__(16) unsigned char stage[TPS * TILEB];   // 64 KB, read-only after barrier
  __shared__ __align__(16) unsigned char jraw[8][2][JBUFB];    // 72 KB, per-wave private

  // ---- stage the split's 8 tile blobs (one pass per tile), single barrier ----
  {
    const uint4* src = (const uint4*)(Spack + (size_t)(sp * TPS) * TILEB);
    #pragma unroll
    for (int ps = 0; ps < TPS; ++ps)
      *(uint4*)&stage[ps*TILEB + tid*16] = src[ps*512 + tid];
  }

  // ---- prologue: f B-fragments in f16, 4 batch groups (register-resident) ----
  // B-frag layout: col = lane&15 (batch), k = (lane>>4)*8 + j (label)
  f16x8 fB[4][2];
  #pragma unroll
  for (int g = 0; g < 4; ++g){
    const float* frow = f + (size_t)(bb + g*16 + c16) * LL;
    #pragma unroll
    for (int kc = 0; kc < 2; ++kc){
      float vv[8];
      *(float4*)&vv[0] = *(const float4*)&frow[kc*32 + 8*q4];
      *(float4*)&vv[4] = *(const float4*)&frow[kc*32 + 8*q4 + 4];
      f16x8 h;
      #pragma unroll
      for (int j = 0; j < 8; ++j) h[j] = (_Float16)vv[j];
      fB[g][kc] = h;
    }
  }

  f32x4 acc2[4][4];                 // [label-tile][batch-group]
  #pragma unroll
  for (int lt = 0; lt < 4; ++lt)
    #pragma unroll
    for (int g = 0; g < 4; ++g) acc2[lt][g] = (f32x4){0.f,0.f,0.f,0.f};
  float zpart[4] = {0.f, 0.f, 0.f, 0.f};

  __syncthreads();                  // stage ready; the ONLY barrier

  // ---- main loop: 8 tiles, waves independent, GEMM2 deferred one tile ----
  #pragma unroll
  for (int t = 0; t < TPS; ++t){
    unsigned char* jcur = &jraw[w][t & 1][0];
    unsigned char* jprv = &jraw[w][(t & 1) ^ 1][0];

    // a1 frags from persistent stage
    f16x8 a1k[4];
    #pragma unroll
    for (int k = 0; k < 4; ++k)
      a1k[k] = *(const f16x8*)&stage[t*TILEB + k*1024 + lane*16];

    // GEMM1: potential tile t (f16), 16 MFMA into p_[ss][g]
    f32x4 p_[2][4];
    #pragma unroll
    for (int ss = 0; ss < 2; ++ss)
      #pragma unroll
      for (int g = 0; g < 4; ++g){
        f32x4 a = (f32x4){0.f,0.f,0.f,0.f};
        a = __builtin_amdgcn_mfma_f32_16x16x32_f16(a1k[ss*2+0], fB[g][0], a, 0,0,0);
        a = __builtin_amdgcn_mfma_f32_16x16x32_f16(a1k[ss*2+1], fB[g][1], a, 0,0,0);
        p_[ss][g] = a;
      }

    // exp -> z -> pack bf16 -> jcur (wave-private)
    #pragma unroll
    for (int ss = 0; ss < 2; ++ss)
      #pragma unroll
      for (int g = 0; g < 4; ++g){
        float J0 = __expf(p_[ss][g][0]);
        float J1 = __expf(p_[ss][g][1]);
        float J2 = __expf(p_[ss][g][2]);
        float J3 = __expf(p_[ss][g][3]);
        zpart[g] += (J0 + J1) + (J2 + J3);
        union { __bf16 h[4]; uint2 u2; } P_;
        P_.h[0] = (__bf16)J0; P_.h[1] = (__bf16)J1;
        P_.h[2] = (__bf16)J2; P_.h[3] = (__bf16)J3;
        *(uint2*)&jcur[(g*16 + c16)*JROWB + ss*32 + q4*8] = P_.u2;
      }

    // deferred GEMM2 for tile t-1: J from jprv (written a full tile ago),
    // a2 re-read from the persistent stage (no register double-buffer)
    if (t > 0){
      bf16x8 b2[4];
      #pragma unroll
      for (int g = 0; g < 4; ++g)
        b2[g] = *(const bf16x8*)&jprv[(g*16 + c16)*JROWB + q4*16];
      bf16x8 a2k[4];
      #pragma unroll
      for (int lt = 0; lt < 4; ++lt)
        a2k[lt] = *(const bf16x8*)&stage[(t-1)*TILEB + 4096 + lt*1024 + lane*16];
      #pragma unroll
      for (int lt = 0; lt < 4; ++lt)
        #pragma unroll
        for (int g = 0; g < 4; ++g)
          acc2[lt][g] = __builtin_amdgcn_mfma_f32_16x16x32_bf16(a2k[lt], b2[g], acc2[lt][g], 0,0,0);
    }
  }

  // drain: GEMM2 for the last tile
  {
    unsigned char* jprv = &jraw[w][(TPS - 1) & 1][0];
    bf16x8 b2[4];
    #pragma unroll
    for (int g = 0; g < 4; ++g)
      b2[g] = *(const bf16x8*)&jprv[(g*16 + c16)*JROWB + q4*16];
    bf16x8 a2k[4];
    #pragma unroll
    for (int lt = 0; lt < 4; ++lt)
      a2k[lt] = *(const bf16x8*)&stage[(TPS-1)*TILEB + 4096 + lt*1024 + lane*16];
    #pragma unroll
    for (int lt = 0; lt < 4; ++lt)
      #pragma unroll
      for (int g = 0; g < 4; ++g)
        acc2[lt][g] = __builtin_amdgcn_mfma_f32_16x16x32_bf16(a2k[lt], b2[g], acc2[lt][g], 0,0,0);
  }

  // ---- epilogue: direct register->global stores, shuffle-reduced z ----
  // acc2 D layout: col = c16 (batch within group g), row = q4*4+jj (label within lt*16)
  float* numOut = numPart + (size_t)sp * BTOT * LL + (size_t)bb * LL;
  #pragma unroll
  for (int lt = 0; lt < 4; ++lt)
    #pragma unroll
    for (int g = 0; g < 4; ++g)
      *(f32x4*)&numOut[(size_t)(g*16 + c16)*LL + lt*16 + q4*4] = acc2[lt][g];

  #pragma unroll
  for (int g = 0; g < 4; ++g){
    float zz = zpart[g];
    zz += __shfl_down(zz, 32);
    zz += __shfl_down(zz, 16);
    if (lane < 16) zPart[(size_t)sp * BTOT + bb + g*16 + lane] = zz;
  }
}

// finalize: sum split partials, p = num/z, BCE, loss via one atomicAdd per block
__global__ void finalize_kernel(const float* __restrict__ numPart,
                                const float* __restrict__ zPart,
                                const float* __restrict__ y,
                                const float* __restrict__ mask,
                                float* __restrict__ out){    // [1 + BTOT*LL]
  int tid = threadIdx.x;
  int idx = blockIdx.x * 256 + tid;      // 0 .. BTOT*LL-1
  int b = idx >> 6;
  float num = 0.f, z = 0.f;
  #pragma unroll
  for (int sp = 0; sp < NSPLIT; ++sp){
    num += numPart[(size_t)sp * BTOT * LL + idx];
    z   += zPart[(size_t)sp * BTOT + b];
  }
  float p = fminf(num / z, 1.0f);
  out[1 + idx] = p;
  float lg = fmaxf(__logf(p), -100.f);
  float l1 = fmaxf(log1pf(-p), -100.f);
  float yv = y[idx], mv = mask[idx];
  float lsum = -(yv*lg + (1.f - yv)*l1) * mv;
  #pragma unroll
  for (int off = 32; off; off >>= 1) lsum += __shfl_down(lsum, off);
  __shared__ float wred[4];
  int w = tid >> 6, lane = tid & 63;
  if (lane == 0) wred[w] = lsum;
  __syncthreads();
  if (tid == 0)
    atomicAdd(&out[0], ((wred[0] + wred[1]) + (wred[2] + wred[3])) * (1.0f / ((float)BTOT * (float)LL)));
}

extern "C" void kernel_launch(void* const* d_in, const int* in_sizes, int n_in,
                              void* d_out, int out_size, void* d_ws, size_t ws_size,
                              hipStream_t stream){
  const float* f = (const float*)d_in[0];
  const float* y = (const float*)d_in[1];
  const float* m = (const float*)d_in[2];
  const float* S = (const float*)d_in[3];
  float* out = (float*)d_out;

  unsigned char* Spack = (unsigned char*)d_ws;                       // 1 MB
  char* p = (char*)d_ws + (size_t)NT * TILEB;
  float* numPart = (float*)p;  p += (size_t)NSPLIT * BTOT * LL * sizeof(float);  // 32 MB
  float* zPart   = (float*)p;                                                    // 512 KB

  prepack_kernel<<<NT, 256, 0, stream>>>(S, Spack, out);
  fused_kernel<<<(BTOT/BT) * NSPLIT, 512, 0, stream>>>(f, Spack, numPart, zPart);
  finalize_kernel<<<(BTOT*LL)/256, 256, 0, stream>>>(numPart, zPart, y, m, out);
}

// Round 11
// 59.149 us; speedup vs baseline: 1.2753x; 1.2753x over previous
//
#include <hip/hip_runtime.h>
#include <stdint.h>

#define BTOT 8192
#define NSS  4096
#define LL   64
#define BT   64            // batches per block (shared by all 4 waves)
#define STT  32            // states per tile
#define NT   (NSS/STT)     // 128 state tiles total
#define NSPLIT 4           // state splits across blocks
#define TPS  (NT/NSPLIT)   // 32 tiles per split; waves interleave (8 each)
#define TILEB 8192         // packed bytes per tile: 4 f16 frags + 4 bf16 frags
#define JROWB 72           // padded LDS row bytes for J tile (64B data + 8 pad)
#define JBUFB (64 * JROWB) // per-wave J buffer: 64 batch rows = 4608 B

typedef __bf16    bf16x8 __attribute__((ext_vector_type(8)));
typedef _Float16  f16x8  __attribute__((ext_vector_type(8)));
typedef float     f32x4  __attribute__((ext_vector_type(4)));

static __device__ __forceinline__ unsigned short f2bf(float x){
  union { float f; uint32_t u; } v; v.f = x;
  uint32_t r = v.u + 0x7fffu + ((v.u >> 16) & 1u);
  return (unsigned short)(r >> 16);
}

// Pack S into per-tile 8KB blobs, fragment-ordered (validated in r6-r10):
//   blob[t][frag*1024 + lane*16], frag 0..3: f16 GEMM1 A-frags (ss*2+kc)
//   blob[t][4096 + lt*1024 + lane*16], lt 0..3: bf16 GEMM2 A-frags
// Also zeroes out[0] (loss accumulator for finalize's atomicAdd).
__global__ void prepack_kernel(const float* __restrict__ S,
                               unsigned char* __restrict__ Spack,
                               float* __restrict__ out){
  const int t = blockIdx.x;
  const int sbase = t * STT;
  if (t == 0 && threadIdx.x == 0) out[0] = 0.f;
  #pragma unroll
  for (int rep = 0; rep < 2; ++rep){
    int item = rep * 256 + threadIdx.x;    // 0..511
    int frag = item >> 6;                  // 0..7
    int lane = item & 63;
    int c16 = lane & 15, q4 = lane >> 4;
    if (frag < 4){
      int ss = frag >> 1, kc = frag & 1;
      const float* row = S + (size_t)(sbase + ss*16 + c16)*LL + kc*32 + q4*8;
      f16x8 h;
      #pragma unroll
      for (int j = 0; j < 8; ++j) h[j] = (_Float16)row[j];   // 0/1 exact
      *(f16x8*)&Spack[(size_t)t*TILEB + frag*1024 + lane*16] = h;
    } else {
      int lt = frag - 4;
      int l  = lt*16 + c16;
      int s0 = sbase + q4*8;
      union { unsigned short u[8]; bf16x8 v; } H;
      #pragma unroll
      for (int j = 0; j < 8; ++j) H.u[j] = f2bf(S[(size_t)(s0 + j)*LL + l]);  // 0/1 exact
      *(bf16x8*)&Spack[(size_t)t*TILEB + 4096 + lt*1024 + lane*16] = H.v;
    }
  }
}

// 4 waves share 64 batches; waves split the 32 tiles (8 each, free-running, no
// barriers in the main loop). Each 8KB tile fetch feeds 64 batches of MFMA work.
__launch_bounds__(256, 2)
__global__ void fused_kernel(const float* __restrict__ f,
                             const unsigned char* __restrict__ Spack,
                             float* __restrict__ numPart,   // [NSPLIT][BTOT][LL]
                             float* __restrict__ zPart){    // [NSPLIT][BTOT]
  const int tid  = threadIdx.x;
  const int w    = tid >> 6;
  const int lane = tid & 63;
  const int c16  = lane & 15;
  const int q4   = lane >> 4;
  const int bt   = blockIdx.x & 127;         // 128 batch-blocks
  const int sp   = blockIdx.x >> 7;          // state split 0..3
  const int bb   = bt * BT;

  // main loop: per-wave J buffers; epilogue (after barrier) aliases the same bytes
  __shared__ __align__(16) unsigned char smem[21248];   // >= max(4*4608, 16896+4096)
  unsigned char* jb = smem + w * JBUFB;

  // ---- prologue: f B-fragments in f16, 4 batch groups (identical in all waves) ----
  // B-frag layout: col = lane&15 (batch), k = (lane>>4)*8 + j (label)
  f16x8 fB[4][2];
  #pragma unroll
  for (int g = 0; g < 4; ++g){
    const float* frow = f + (size_t)(bb + g*16 + c16) * LL;
    #pragma unroll
    for (int kc = 0; kc < 2; ++kc){
      float vv[8];
      *(float4*)&vv[0] = *(const float4*)&frow[kc*32 + 8*q4];
      *(float4*)&vv[4] = *(const float4*)&frow[kc*32 + 8*q4 + 4];
      f16x8 h;
      #pragma unroll
      for (int j = 0; j < 8; ++j) h[j] = (_Float16)vv[j];
      fB[g][kc] = h;
    }
  }

  f32x4 acc2[4][4];                 // [label-tile][batch-group]
  #pragma unroll
  for (int lt = 0; lt < 4; ++lt)
    #pragma unroll
    for (int g = 0; g < 4; ++g) acc2[lt][g] = (f32x4){0.f,0.f,0.f,0.f};
  float zpart[4] = {0.f, 0.f, 0.f, 0.f};

  const int tbase = sp * TPS;

  #pragma unroll
  for (int ii = 0; ii < TPS/4; ++ii){
    const int t = tbase + w + ii*4;
    const unsigned char* blob = Spack + (size_t)t * TILEB;

    // a1 frags (4 coalesced 1KB loads), then GEMM1 (f16): 16 MFMA
    f16x8 a1k[4];
    #pragma unroll
    for (int k = 0; k < 4; ++k)
      a1k[k] = *(const f16x8*)&blob[k*1024 + lane*16];
    f32x4 p_[2][4];
    #pragma unroll
    for (int ss = 0; ss < 2; ++ss)
      #pragma unroll
      for (int g = 0; g < 4; ++g){
        f32x4 a = (f32x4){0.f,0.f,0.f,0.f};
        a = __builtin_amdgcn_mfma_f32_16x16x32_f16(a1k[ss*2+0], fB[g][0], a, 0,0,0);
        a = __builtin_amdgcn_mfma_f32_16x16x32_f16(a1k[ss*2+1], fB[g][1], a, 0,0,0);
        p_[ss][g] = a;
      }

    // a2 frags issued here: L2 latency hides under exp/pack below
    bf16x8 a2k[4];
    #pragma unroll
    for (int lt = 0; lt < 4; ++lt)
      a2k[lt] = *(const bf16x8*)&blob[4096 + lt*1024 + lane*16];

    // exp -> z -> pack bf16 -> wave-private J (row = batch, col = state)
    #pragma unroll
    for (int ss = 0; ss < 2; ++ss)
      #pragma unroll
      for (int g = 0; g < 4; ++g){
        float J0 = __expf(p_[ss][g][0]);
        float J1 = __expf(p_[ss][g][1]);
        float J2 = __expf(p_[ss][g][2]);
        float J3 = __expf(p_[ss][g][3]);
        zpart[g] += (J0 + J1) + (J2 + J3);
        union { __bf16 h[4]; uint2 u2; } P_;
        P_.h[0] = (__bf16)J0; P_.h[1] = (__bf16)J1;
        P_.h[2] = (__bf16)J2; P_.h[3] = (__bf16)J3;
        *(uint2*)&jb[(g*16 + c16)*JROWB + ss*32 + q4*8] = P_.u2;
      }

    // J B-frags (same-wave LDS RAW, compiler lgkmcnt) + GEMM2 (bf16): 16 MFMA
    bf16x8 b2[4];
    #pragma unroll
    for (int g = 0; g < 4; ++g)
      b2[g] = *(const bf16x8*)&jb[(g*16 + c16)*JROWB + q4*16];
    #pragma unroll
    for (int lt = 0; lt < 4; ++lt)
      #pragma unroll
      for (int g = 0; g < 4; ++g)
        acc2[lt][g] = __builtin_amdgcn_mfma_f32_16x16x32_bf16(a2k[lt], b2[g], acc2[lt][g], 0,0,0);
  }

  // ---- epilogue: cross-wave reduce through aliased LDS (J buffers dead) ----
  __syncthreads();
  float* nredQ = (float*)smem;               // [4][16*66] = 16896 B
  float* zred  = (float*)(smem + 16896);     // [4][256]   = 4096 B
  float* numOut = numPart + (size_t)sp * BTOT * LL + (size_t)bb * LL;

  #pragma unroll
  for (int g = 0; g < 4; ++g)
    zred[w*256 + q4*64 + g*16 + c16] = zpart[g];

  #pragma unroll
  for (int lt = 0; lt < 4; ++lt){
    #pragma unroll
    for (int g = 0; g < 4; ++g)
      #pragma unroll
      for (int jj = 0; jj < 4; ++jj)
        nredQ[w*1056 + (q4*4 + jj)*66 + g*16 + c16] = acc2[lt][g][jj];
    __syncthreads();
    if (lt == 0 && tid < BT){
      float zz = 0.f;
      #pragma unroll
      for (int ww = 0; ww < 4; ++ww)
        #pragma unroll
        for (int qq = 0; qq < 4; ++qq) zz += zred[ww*256 + qq*64 + tid];
      zPart[(size_t)sp * BTOT + bb + tid] = zz;
    }
    #pragma unroll
    for (int it = 0; it < 4; ++it){
      int idx = it*256 + tid;          // 0..1023: 64 batches x 16 labels
      int b = idx >> 4, l = idx & 15;
      float v = (nredQ[0*1056 + l*66 + b] + nredQ[1*1056 + l*66 + b])
              + (nredQ[2*1056 + l*66 + b] + nredQ[3*1056 + l*66 + b]);
      numOut[(size_t)b*LL + lt*16 + l] = v;
    }
    __syncthreads();
  }
}

// finalize: sum split partials, p = num/z, BCE, loss via one atomicAdd per block
__global__ void finalize_kernel(const float* __restrict__ numPart,
                                const float* __restrict__ zPart,
                                const float* __restrict__ y,
                                const float* __restrict__ mask,
                                float* __restrict__ out){    // [1 + BTOT*LL]
  int tid = threadIdx.x;
  int idx = blockIdx.x * 256 + tid;      // 0 .. BTOT*LL-1
  int b = idx >> 6;
  float num = 0.f, z = 0.f;
  #pragma unroll
  for (int sp = 0; sp < NSPLIT; ++sp){
    num += numPart[(size_t)sp * BTOT * LL + idx];
    z   += zPart[(size_t)sp * BTOT + b];
  }
  float p = fminf(num / z, 1.0f);
  out[1 + idx] = p;
  float lg = fmaxf(__logf(p), -100.f);
  float l1 = fmaxf(log1pf(-p), -100.f);
  float yv = y[idx], mv = mask[idx];
  float lsum = -(yv*lg + (1.f - yv)*l1) * mv;
  #pragma unroll
  for (int off = 32; off; off >>= 1) lsum += __shfl_down(lsum, off);
  __shared__ float wred[4];
  int w = tid >> 6, lane = tid & 63;
  if (lane == 0) wred[w] = lsum;
  __syncthreads();
  if (tid == 0)
    atomicAdd(&out[0], ((wred[0] + wred[1]) + (wred[2] + wred[3])) * (1.0f / ((float)BTOT * (float)LL)));
}

extern "C" void kernel_launch(void* const* d_in, const int* in_sizes, int n_in,
                              void* d_out, int out_size, void* d_ws, size_t ws_size,
                              hipStream_t stream){
  const float* f = (const float*)d_in[0];
  const float* y = (const float*)d_in[1];
  const float* m = (const float*)d_in[2];
  const float* S = (const float*)d_in[3];
  float* out = (float*)d_out;

  unsigned char* Spack = (unsigned char*)d_ws;                       // 1 MB
  char* p = (char*)d_ws + (size_t)NT * TILEB;
  float* numPart = (float*)p;  p += (size_t)NSPLIT * BTOT * LL * sizeof(float);  // 8 MB
  float* zPart   = (float*)p;                                                    // 128 KB

  prepack_kernel<<<NT, 256, 0, stream>>>(S, Spack, out);
  fused_kernel<<<(BTOT/BT) * NSPLIT, 256, 0, stream>>>(f, Spack, numPart, zPart);
  finalize_kernel<<<(BTOT*LL)/256, 256, 0, stream>>>(numPart, zPart, y, m, out);
}